// Round 1
// baseline (76.732 us; speedup 1.0000x reference)
//
#include <hip/hip_runtime.h>

// Problem constants (fixed by the harness: B=4096, K=128, C=64)
#define K_KP   128
#define C_COMP 64
#define TK     16      // k-columns per block
#define TBW    16      // b-slots (thread rows) per block
#define NB     4       // b values per thread  -> block covers 64 b x 16 k
#define LDS_STRIDE 516 // floats per k row: 64*8 + 4 pad (bank de-conflict: 516%32=4)

#if __has_builtin(__builtin_amdgcn_exp2f)
#define EXP2F(x) __builtin_amdgcn_exp2f(x)
#else
#define EXP2F(x) exp2f(x)
#endif
#if __has_builtin(__builtin_amdgcn_logf)
#define LOG2F_(x) __builtin_amdgcn_logf(x)
#else
#define LOG2F_(x) __log2f(x)
#endif
#if __has_builtin(__builtin_amdgcn_rcpf)
#define RCPF(x) __builtin_amdgcn_rcpf(x)
#else
#define RCPF(x) (1.0f/(x))
#endif
#if __has_builtin(__builtin_amdgcn_rsqf)
#define RSQF(x) __builtin_amdgcn_rsqf(x)
#else
#define RSQF(x) rsqrtf(x)
#endif

__global__ __launch_bounds__(256) void recovery_kernel(
    const float* __restrict__ z,       // [B,K,2]
    const float* __restrict__ weights, // [K,C]
    const float* __restrict__ means,   // [K,C,2]
    const float* __restrict__ covs,    // [K,C,2,2]
    const float* __restrict__ scale,   // [K,2]
    float* __restrict__ out, int B)
{
    __shared__ float lds[TK * LDS_STRIDE];   // 33,024 B

    const int t  = threadIdx.x;
    const int kb = blockIdx.x & 7;           // K/TK = 8 k-blocks
    const int bb = blockIdx.x >> 3;
    const int k0 = kb * TK;
    const int b0 = bb * (TBW * NB);

    // ---- stage per-(k,c) derived params into LDS ----
    // per comp (8 floats): m0, m1, k2*i00, k2*i01, k2*i11, lc, pad, pad
    const float K2       = 0.72134752044f;   // 0.5 * log2(e)
    const float LOG2_2PI = 2.6514961295f;    // log2(2*pi)
    for (int i = t; i < TK * C_COMP; i += 256) {
        int kl = i >> 6;
        int c  = i & 63;
        int g  = (k0 + kl) * C_COMP + c;
        float w  = weights[g];
        float m0 = means[2*g], m1 = means[2*g + 1];
        float a  = covs[4*g],     bq = covs[4*g + 1];
        float cq = covs[4*g + 2], d  = covs[4*g + 3];
        float det  = a*d - bq*cq;
        float rdet = RCPF(det);
        float i00 = d  * rdet * K2;
        float i01 = -bq * rdet * K2;
        float i11 = a  * rdet * K2;
        // lc = log2(w) - log2(2pi) - 0.5*log2(det)
        float lc = LOG2F_(w) - LOG2_2PI - 0.5f * LOG2F_(det);
        float* p = &lds[kl * LDS_STRIDE + c * 8];
        ((float4*)p)[0] = make_float4(m0, m1, i00, i01);
        ((float2*)(p + 4))[0] = make_float2(i11, lc);
    }
    __syncthreads();

    const int kl = t & 15;
    const int bl = t >> 4;
    const int kg = k0 + kl;

    // ---- load this thread's NB z values (coalesced float2) ----
    const float2* z2 = (const float2*)z;     // [B*K]
    float zx[NB], zy[NB];
#pragma unroll
    for (int j = 0; j < NB; ++j) {
        int b = b0 + bl + j * TBW;
        float2 v = z2[(size_t)b * K_KP + kg];
        zx[j] = v.x; zy[j] = v.y;
    }

    float pdf[NB], gs0[NB], gs1[NB];
#pragma unroll
    for (int j = 0; j < NB; ++j) { pdf[j] = 0.0f; gs0[j] = 0.0f; gs1[j] = 0.0f; }

    const float* kp = &lds[kl * LDS_STRIDE];
#pragma unroll 8
    for (int c = 0; c < C_COMP; ++c) {
        float4 A  = *(const float4*)(kp + c * 8);
        float2 Bv = *(const float2*)(kp + c * 8 + 4);
        float m0 = A.x, m1 = A.y, i00 = A.z, i01 = A.w;
        float i11 = Bv.x, lc = Bv.y;
#pragma unroll
        for (int j = 0; j < NB; ++j) {
            float d0 = zx[j] - m0;
            float d1 = zy[j] - m1;
            float s0 = fmaf(i01, d1, i00 * d0);   // k2 * (Sigma^-1 diff)_0
            float s1 = fmaf(i01, d0, i11 * d1);   // k2 * (Sigma^-1 diff)_1
            float arg = fmaf(-d1, s1, lc);
            arg = fmaf(-d0, s0, arg);             // lc - k2*maha
            float e = EXP2F(arg);                 // = w/(2pi sqrt(det)) * exp(-maha/2)
            pdf[j] += e;
            gs0[j] = fmaf(e, s0, gs0[j]);
            gs1[j] = fmaf(e, s1, gs1[j]);
        }
    }

    // ---- epilogue ----
    float2 sc = ((const float2*)scale)[kg];
    const float NEG_INV_K2 = -1.3862943611f;     // -1/K2 = -2 ln 2
    float f0 = sc.x * NEG_INV_K2;                // fold unnorm scale + sign + 1/k2
    float f1 = sc.y * NEG_INV_K2;
    const int KK2 = 2 * K_KP;                    // 256
    float* out0 = out;
    float* out1 = out + (size_t)B * KK2;
#pragma unroll
    for (int j = 0; j < NB; ++j) {
        int b = b0 + bl + j * TBW;
        // density_norm = sigmoid((pdf + eps)/tau) = sigmoid(2*pdf - 1)
        float x  = 2.0f * pdf[j] - 1.0f;
        float ex = EXP2F(-1.44269504f * x);
        float dn = RCPF(1.0f + ex);
        // gradient branch
        float g0 = gs0[j] * f0;                  // grad_raw
        float g1 = gs1[j] * f1;
        float n2 = fmaf(g0, g0, g1 * g1);
        float rn = RSQF(n2);
        float nrm = n2 * rn;                     // |grad_raw|
        // mag = exp((5500 - nrm)/1100) = exp2(7.2134752 - nrm*log2(e)/1100)
        float mag = EXP2F(fmaf(nrm, -0.0013115409f, 7.2134752044f));
        float m = rn * mag;
        ((float2*)(out0 + (size_t)b * KK2 + 2 * kg))[0] = make_float2(dn, dn);
        ((float2*)(out1 + (size_t)b * KK2 + 2 * kg))[0] = make_float2(g0 * m, g1 * m);
    }
}

extern "C" void kernel_launch(void* const* d_in, const int* in_sizes, int n_in,
                              void* d_out, int out_size, void* d_ws, size_t ws_size,
                              hipStream_t stream) {
    const float* z       = (const float*)d_in[0];
    const float* weights = (const float*)d_in[1];
    const float* means   = (const float*)d_in[2];
    const float* covs    = (const float*)d_in[3];
    const float* scale   = (const float*)d_in[4];
    float* out = (float*)d_out;

    int B = in_sizes[0] / (2 * K_KP);            // 4096
    int grid = (K_KP / TK) * (B / (TBW * NB));   // 8 * 64 = 512 blocks
    recovery_kernel<<<grid, 256, 0, stream>>>(z, weights, means, covs, scale, out, B);
}

// Round 2
// 76.205 us; speedup vs baseline: 1.0069x; 1.0069x over previous
//
#include <hip/hip_runtime.h>

// Problem constants (fixed by the harness: B=4096, K=128, C=64)
#define K_KP   128
#define C_COMP 64
#define TK     16      // k-columns per block
#define TBW    16      // b-slots (thread rows) per block
#define NB     2       // b values per thread -> block covers 32 b x 16 k
#define LDS_STRIDE 516 // floats per k row: 64*8 + 4 pad (bank de-conflict: 516%32=4)

#if __has_builtin(__builtin_amdgcn_exp2f)
#define EXP2F(x) __builtin_amdgcn_exp2f(x)
#else
#define EXP2F(x) exp2f(x)
#endif
#if __has_builtin(__builtin_amdgcn_logf)
#define LOG2F_(x) __builtin_amdgcn_logf(x)
#else
#define LOG2F_(x) __log2f(x)
#endif
#if __has_builtin(__builtin_amdgcn_rcpf)
#define RCPF(x) __builtin_amdgcn_rcpf(x)
#else
#define RCPF(x) (1.0f/(x))
#endif
#if __has_builtin(__builtin_amdgcn_rsqf)
#define RSQF(x) __builtin_amdgcn_rsqf(x)
#else
#define RSQF(x) rsqrtf(x)
#endif

// 256 threads (4 waves), min 4 waves/EU -> 4 blocks/CU, VGPR cap 128
__global__ __launch_bounds__(256, 4) void recovery_kernel(
    const float* __restrict__ z,       // [B,K,2]
    const float* __restrict__ weights, // [K,C]
    const float* __restrict__ means,   // [K,C,2]
    const float* __restrict__ covs,    // [K,C,2,2]
    const float* __restrict__ scale,   // [K,2]
    float* __restrict__ out, int B)
{
    __shared__ float lds[TK * LDS_STRIDE];   // 33,024 B -> 4 blocks/CU fits 132KB/160KB

    const int t  = threadIdx.x;
    const int kb = blockIdx.x & 7;           // K/TK = 8 k-blocks
    const int bb = blockIdx.x >> 3;
    const int k0 = kb * TK;
    const int b0 = bb * (TBW * NB);

    // ---- stage per-(k,c) derived params into LDS ----
    // per comp (8 floats): m0, m1, k2*i00, k2*i01, k2*i11, lc, pad, pad
    const float K2       = 0.72134752044f;   // 0.5 * log2(e)
    const float LOG2_2PI = 2.6514961295f;    // log2(2*pi)
    for (int i = t; i < TK * C_COMP; i += 256) {
        int kl = i >> 6;
        int c  = i & 63;
        int g  = (k0 + kl) * C_COMP + c;
        float w  = weights[g];
        float m0 = means[2*g], m1 = means[2*g + 1];
        float a  = covs[4*g],     bq = covs[4*g + 1];
        float cq = covs[4*g + 2], d  = covs[4*g + 3];
        float det  = a*d - bq*cq;
        float rdet = RCPF(det);
        float i00 = d  * rdet * K2;
        float i01 = -bq * rdet * K2;
        float i11 = a  * rdet * K2;
        // lc = log2(w) - log2(2pi) - 0.5*log2(det)
        float lc = LOG2F_(w) - LOG2_2PI - 0.5f * LOG2F_(det);
        float* p = &lds[kl * LDS_STRIDE + c * 8];
        ((float4*)p)[0] = make_float4(m0, m1, i00, i01);
        ((float2*)(p + 4))[0] = make_float2(i11, lc);
    }
    __syncthreads();

    const int kl = t & 15;
    const int bl = t >> 4;
    const int kg = k0 + kl;

    // ---- load this thread's NB z values (coalesced float2) ----
    const float2* z2 = (const float2*)z;     // [B*K]
    float zx[NB], zy[NB];
#pragma unroll
    for (int j = 0; j < NB; ++j) {
        int b = b0 + bl + j * TBW;
        float2 v = z2[(size_t)b * K_KP + kg];
        zx[j] = v.x; zy[j] = v.y;
    }

    float pdf[NB], gs0[NB], gs1[NB];
#pragma unroll
    for (int j = 0; j < NB; ++j) { pdf[j] = 0.0f; gs0[j] = 0.0f; gs1[j] = 0.0f; }

    const float* kp = &lds[kl * LDS_STRIDE];
#pragma unroll 4
    for (int c = 0; c < C_COMP; ++c) {
        float4 A  = *(const float4*)(kp + c * 8);
        float2 Bv = *(const float2*)(kp + c * 8 + 4);
        float m0 = A.x, m1 = A.y, i00 = A.z, i01 = A.w;
        float i11 = Bv.x, lc = Bv.y;
#pragma unroll
        for (int j = 0; j < NB; ++j) {
            float d0 = zx[j] - m0;
            float d1 = zy[j] - m1;
            float s0 = fmaf(i01, d1, i00 * d0);   // k2 * (Sigma^-1 diff)_0
            float s1 = fmaf(i01, d0, i11 * d1);   // k2 * (Sigma^-1 diff)_1
            float arg = fmaf(-d1, s1, lc);
            arg = fmaf(-d0, s0, arg);             // lc - k2*maha
            float e = EXP2F(arg);                 // = w/(2pi sqrt(det)) * exp(-maha/2)
            pdf[j] += e;
            gs0[j] = fmaf(e, s0, gs0[j]);
            gs1[j] = fmaf(e, s1, gs1[j]);
        }
    }

    // ---- epilogue ----
    float2 sc = ((const float2*)scale)[kg];
    const float NEG_INV_K2 = -1.3862943611f;     // -1/K2 = -2 ln 2
    float f0 = sc.x * NEG_INV_K2;                // fold unnorm scale + sign + 1/k2
    float f1 = sc.y * NEG_INV_K2;
    const int KK2 = 2 * K_KP;                    // 256
    float* out0 = out;
    float* out1 = out + (size_t)B * KK2;
#pragma unroll
    for (int j = 0; j < NB; ++j) {
        int b = b0 + bl + j * TBW;
        // density_norm = sigmoid((pdf + eps)/tau) = sigmoid(2*pdf - 1)
        float x  = 2.0f * pdf[j] - 1.0f;
        float ex = EXP2F(-1.44269504f * x);
        float dn = RCPF(1.0f + ex);
        // gradient branch
        float g0 = gs0[j] * f0;                  // grad_raw
        float g1 = gs1[j] * f1;
        float n2 = fmaf(g0, g0, g1 * g1);
        float rn = RSQF(n2);
        float nrm = n2 * rn;                     // |grad_raw|
        // mag = exp((5500 - nrm)/1100) = exp2(7.2134752 - nrm*log2(e)/1100)
        float mag = EXP2F(fmaf(nrm, -0.0013115409f, 7.2134752044f));
        float m = rn * mag;
        ((float2*)(out0 + (size_t)b * KK2 + 2 * kg))[0] = make_float2(dn, dn);
        ((float2*)(out1 + (size_t)b * KK2 + 2 * kg))[0] = make_float2(g0 * m, g1 * m);
    }
}

extern "C" void kernel_launch(void* const* d_in, const int* in_sizes, int n_in,
                              void* d_out, int out_size, void* d_ws, size_t ws_size,
                              hipStream_t stream) {
    const float* z       = (const float*)d_in[0];
    const float* weights = (const float*)d_in[1];
    const float* means   = (const float*)d_in[2];
    const float* covs    = (const float*)d_in[3];
    const float* scale   = (const float*)d_in[4];
    float* out = (float*)d_out;

    int B = in_sizes[0] / (2 * K_KP);            // 4096
    int grid = (K_KP / TK) * (B / (TBW * NB));   // 8 * 128 = 1024 blocks
    recovery_kernel<<<grid, 256, 0, stream>>>(z, weights, means, covs, scale, out, B);
}

// Round 3
// 73.263 us; speedup vs baseline: 1.0473x; 1.0402x over previous
//
#include <hip/hip_runtime.h>

// Problem constants (fixed by the harness: B=4096, K=128, C=64)
#define K_KP   128
#define C_COMP 64
#define TK     8       // k-columns per block
#define TBS    32      // b-slots per block (threads = TK*TBS = 256)
#define NB     4       // b values per thread -> block covers 128 b x 8 k
#define LDS_STRIDE 388 // floats per k row: 32 c-pairs * 12 + 4 pad (388%32=4 -> 8 rows cover all banks)

typedef float v2f __attribute__((ext_vector_type(2)));

#if __has_builtin(__builtin_amdgcn_exp2f)
#define EXP2F(x) __builtin_amdgcn_exp2f(x)
#else
#define EXP2F(x) exp2f(x)
#endif
#if __has_builtin(__builtin_amdgcn_logf)
#define LOG2F_(x) __builtin_amdgcn_logf(x)
#else
#define LOG2F_(x) __log2f(x)
#endif
#if __has_builtin(__builtin_amdgcn_rcpf)
#define RCPF(x) __builtin_amdgcn_rcpf(x)
#else
#define RCPF(x) (1.0f/(x))
#endif
#if __has_builtin(__builtin_amdgcn_rsqf)
#define RSQF(x) __builtin_amdgcn_rsqf(x)
#else
#define RSQF(x) rsqrtf(x)
#endif

// per c-pair eval on a v2f pair of b-values; relies on -ffp-contract for pk_fma
#define EVAL(m0, m1, i00, i01, i11, lc, ZX, ZY, PDF, G0, G1)            \
    {                                                                   \
        v2f d0 = ZX - (m0);                                             \
        v2f d1 = ZY - (m1);                                             \
        v2f s0 = (i00) * d0 + (i01) * d1;  /* k2 * (Sigma^-1 diff)_0 */ \
        v2f s1 = (i01) * d0 + (i11) * d1;                               \
        v2f arg = (lc) - d0 * s0 - d1 * s1; /* lc - k2*maha */          \
        v2f e;                                                          \
        e.x = EXP2F(arg.x);                                             \
        e.y = EXP2F(arg.y);                                             \
        PDF += e;                                                       \
        G0 += e * s0;                                                   \
        G1 += e * s1;                                                   \
    }

// 256 threads (4 waves), min 4 waves/EU -> 4 blocks/CU (16 waves/CU)
__global__ __launch_bounds__(256, 4) void recovery_kernel(
    const float* __restrict__ z,       // [B,K,2]
    const float* __restrict__ weights, // [K,C]
    const float* __restrict__ means,   // [K,C,2]
    const float* __restrict__ covs,    // [K,C,2,2]
    const float* __restrict__ scale,   // [K,2]
    float* __restrict__ out, int B)
{
    __shared__ float lds[TK * LDS_STRIDE];   // 12,416 B -> 4 blocks/CU trivially fits

    const int t  = threadIdx.x;
    const int kb = blockIdx.x & 15;          // K/TK = 16 k-blocks
    const int bb = blockIdx.x >> 4;
    const int k0 = kb * TK;
    const int b0 = bb * (TBS * NB);          // 128 b per block

    // ---- stage per-(k,c) derived params into LDS ----
    // layout per k-row, per c-pair p (12 floats):
    //   [m0,m1,i00,i01]_{c=2p}  [m0,m1,i00,i01]_{c=2p+1}  [i11,lc]_{2p} [i11,lc]_{2p+1}
    const float K2       = 0.72134752044f;   // 0.5 * log2(e)
    const float LOG2_2PI = 2.6514961295f;    // log2(2*pi)
    for (int i = t; i < TK * C_COMP; i += 256) {
        int kl = i >> 6;                     // 0..7
        int c  = i & 63;
        int g  = (k0 + kl) * C_COMP + c;
        float w  = weights[g];
        float m0 = means[2*g], m1 = means[2*g + 1];
        float a  = covs[4*g],     bq = covs[4*g + 1];
        float cq = covs[4*g + 2], d  = covs[4*g + 3];
        float det  = a*d - bq*cq;
        float rdet = RCPF(det);
        float i00 = d  * rdet * K2;
        float i01 = -bq * rdet * K2;
        float i11 = a  * rdet * K2;
        float lc = LOG2F_(w) - LOG2_2PI - 0.5f * LOG2F_(det);
        float* row = &lds[kl * LDS_STRIDE + (c >> 1) * 12];
        ((float4*)(row + (c & 1) * 4))[0] = make_float4(m0, m1, i00, i01);
        ((float2*)(row + 8 + (c & 1) * 2))[0] = make_float2(i11, lc);
    }
    __syncthreads();

    const int kl = t & 7;
    const int bl = t >> 3;                   // 0..31
    const int kg = k0 + kl;

    // ---- load this thread's NB z values (coalesced float2: 64B per 8 lanes) ----
    const float2* z2 = (const float2*)z;     // [B*K]
    float zx[NB], zy[NB];
#pragma unroll
    for (int j = 0; j < NB; ++j) {
        int b = b0 + bl + j * TBS;
        float2 v = z2[(size_t)b * K_KP + kg];
        zx[j] = v.x; zy[j] = v.y;
    }

    v2f ZXa = {zx[0], zx[1]}, ZXb = {zx[2], zx[3]};
    v2f ZYa = {zy[0], zy[1]}, ZYb = {zy[2], zy[3]};
    v2f pdfa = {0.f, 0.f}, pdfb = {0.f, 0.f};
    v2f g0a  = {0.f, 0.f}, g0b  = {0.f, 0.f};
    v2f g1a  = {0.f, 0.f}, g1b  = {0.f, 0.f};

    const float* kp = &lds[kl * LDS_STRIDE];
#pragma unroll 4
    for (int p = 0; p < C_COMP / 2; ++p) {
        float4 A0 = *(const float4*)(kp + p * 12);
        float4 A1 = *(const float4*)(kp + p * 12 + 4);
        float4 Bp = *(const float4*)(kp + p * 12 + 8);
        EVAL(A0.x, A0.y, A0.z, A0.w, Bp.x, Bp.y, ZXa, ZYa, pdfa, g0a, g1a);
        EVAL(A0.x, A0.y, A0.z, A0.w, Bp.x, Bp.y, ZXb, ZYb, pdfb, g0b, g1b);
        EVAL(A1.x, A1.y, A1.z, A1.w, Bp.z, Bp.w, ZXa, ZYa, pdfa, g0a, g1a);
        EVAL(A1.x, A1.y, A1.z, A1.w, Bp.z, Bp.w, ZXb, ZYb, pdfb, g0b, g1b);
    }

    float pdf[NB] = {pdfa.x, pdfa.y, pdfb.x, pdfb.y};
    float gs0[NB] = {g0a.x, g0a.y, g0b.x, g0b.y};
    float gs1[NB] = {g1a.x, g1a.y, g1b.x, g1b.y};

    // ---- epilogue ----
    float2 sc = ((const float2*)scale)[kg];
    const float NEG_INV_K2 = -1.3862943611f;     // -1/K2 = -2 ln 2
    float f0 = sc.x * NEG_INV_K2;                // fold unnorm scale + sign + 1/k2
    float f1 = sc.y * NEG_INV_K2;
    const int KK2 = 2 * K_KP;                    // 256
    float* out0 = out;
    float* out1 = out + (size_t)B * KK2;
#pragma unroll
    for (int j = 0; j < NB; ++j) {
        int b = b0 + bl + j * TBS;
        // density_norm = sigmoid((pdf + eps)/tau) = sigmoid(2*pdf - 1)
        float x  = 2.0f * pdf[j] - 1.0f;
        float ex = EXP2F(-1.44269504f * x);
        float dn = RCPF(1.0f + ex);
        // gradient branch
        float g0 = gs0[j] * f0;                  // grad_raw
        float g1 = gs1[j] * f1;
        float n2 = fmaf(g0, g0, g1 * g1);
        float rn = RSQF(n2);
        float nrm = n2 * rn;                     // |grad_raw|
        // mag = exp((5500 - nrm)/1100) = exp2(7.2134752 - nrm*log2(e)/1100)
        float mag = EXP2F(fmaf(nrm, -0.0013115409f, 7.2134752044f));
        float m = rn * mag;
        ((float2*)(out0 + (size_t)b * KK2 + 2 * kg))[0] = make_float2(dn, dn);
        ((float2*)(out1 + (size_t)b * KK2 + 2 * kg))[0] = make_float2(g0 * m, g1 * m);
    }
}

extern "C" void kernel_launch(void* const* d_in, const int* in_sizes, int n_in,
                              void* d_out, int out_size, void* d_ws, size_t ws_size,
                              hipStream_t stream) {
    const float* z       = (const float*)d_in[0];
    const float* weights = (const float*)d_in[1];
    const float* means   = (const float*)d_in[2];
    const float* covs    = (const float*)d_in[3];
    const float* scale   = (const float*)d_in[4];
    float* out = (float*)d_out;

    int B = in_sizes[0] / (2 * K_KP);            // 4096
    int grid = (K_KP / TK) * (B / (TBS * NB));   // 16 * 32 = 512... see below
    recovery_kernel<<<grid, 256, 0, stream>>>(z, weights, means, covs, scale, out, B);
}